// Round 17
// baseline (59.280 us; speedup 1.0000x reference)
//
#include <hip/hip_runtime.h>
#include <hip/hip_bf16.h>
#include <stdint.h>

// NT-Xent loss, B=4096, D=256, T=0.5, eps=1e-8.
// loss_r = log(sum_{c!=r} exp(2*dot(zn_r,zn_c))) - 2*dot(zin_r, zjn_r); out = mean.
// zn_s = zn * sqrt(2*log2e) stored bf16 -> MFMA acc = 2*log2e*dot -> exp2(acc) direct.
// Diagonal accumulated unconditionally; subtracted in k_loss via exp2(diag).
//
// R17: COUNTED-VMCNT 3-BUFFER PIPELINE (T3+T4+T5). R1..R16 ledger: every 2-barrier
// variant = ~43us (MfmaUtil ~30%, both pipes idle, clean counters) = the structure's
// ceiling; compiler drains vmcnt(0) at barriers AND before ds_reads that may alias
// in-flight global_load_lds (same LDS object). Fix: 3 SEPARATE __shared__ buffers
// (distinct objects -> no-alias), stage s+2 while computing s, raw s_barrier with
// manual s_waitcnt vmcnt(4) (never 0 in steady state), x3-unrolled loop for static
// buffer names, setprio(1) around MFMA clusters.
//
// LESSONS: 512-thr blocks always spill; launch_bounds arg2 caps arch-VGPR ~256/arg2;
// grid>512 thrashes L2. Health: VGPR<=128, WRITE<1MB, FETCH~17MB, conflicts 0.

#define BROWS 4096
#define DIM   256
#define N2    8192

typedef __attribute__((ext_vector_type(4))) float          f32x4;
typedef __attribute__((ext_vector_type(8))) short          s16x8;
typedef __attribute__((ext_vector_type(4))) unsigned short u16x4;

#define S_EXP  1.6986436597467051f   /* sqrt(2*log2(e)) */
#define LN2    0.6931471805599453f

__device__ inline unsigned short f2bf(float f) {
    uint32_t b = __float_as_uint(f);
    b += 0x7fffu + ((b >> 16) & 1u);   // RNE
    return (unsigned short)(b >> 16);
}
__device__ inline float bf2f(unsigned short u) {
    return __uint_as_float(((uint32_t)u) << 16);
}

__device__ inline void gload_lds16(const void* g, void* l) {
    __builtin_amdgcn_global_load_lds(
        (const __attribute__((address_space(1))) uint32_t*)g,
        (__attribute__((address_space(3))) uint32_t*)l, 16, 0, 0);
}

__device__ inline float wave_reduce(float v) {
    #pragma unroll
    for (int m = 1; m < 64; m <<= 1) v += __shfl_xor(v, m);
    return v;
}

// ---- K1: fused normalize (both views) + positive-pair exponent + diag self-dot ----
__global__ __launch_bounds__(256) void k_norm_pos(const float* __restrict__ zi,
                                                  const float* __restrict__ zj,
                                                  unsigned short* __restrict__ zn,
                                                  float* __restrict__ diag,
                                                  float* __restrict__ posv,
                                                  unsigned int* __restrict__ counter) {
    if (blockIdx.x == 0 && threadIdx.x == 0) *counter = 0u;
    int i    = blockIdx.x * 4 + (threadIdx.x >> 6);
    int lane = threadIdx.x & 63;
    f32x4 a = *(const f32x4*)(zi + (size_t)i * DIM + lane * 4);
    f32x4 b = *(const f32x4*)(zj + (size_t)i * DIM + lane * 4);
    float ssa = a[0]*a[0] + a[1]*a[1] + a[2]*a[2] + a[3]*a[3];
    float ssb = b[0]*b[0] + b[1]*b[1] + b[2]*b[2] + b[3]*b[3];
    float dab = a[0]*b[0] + a[1]*b[1] + a[2]*b[2] + a[3]*b[3];
    ssa = wave_reduce(ssa);
    ssb = wave_reduce(ssb);
    dab = wave_reduce(dab);
    float na = 1.0f / fmaxf(sqrtf(ssa), 1e-8f);
    float nb = 1.0f / fmaxf(sqrtf(ssb), 1e-8f);
    if (lane == 0) posv[i] = 2.0f * dab * na * nb;   // natural-log exponent of pos pair

    float sa = na * S_EXP, sb = nb * S_EXP;
    u16x4 oa, ob;
    float da = 0.0f, db = 0.0f;
    #pragma unroll
    for (int k = 0; k < 4; ++k) {
        unsigned short ua = f2bf(a[k] * sa);
        unsigned short ub = f2bf(b[k] * sb);
        oa[k] = ua; ob[k] = ub;
        float fa = bf2f(ua), fb = bf2f(ub);
        da += fa * fa; db += fb * fb;
    }
    *(u16x4*)(zn + (size_t)i * DIM + lane * 4)           = oa;
    *(u16x4*)(zn + (size_t)(i + BROWS) * DIM + lane * 4) = ob;
    da = wave_reduce(da);
    db = wave_reduce(db);
    if (lane == 0) { diag[i] = da; diag[i + BROWS] = db; }
}

// ---- K2: fused sim GEMM + exp2 + row-sum, counted-vmcnt 3-buffer pipeline ----
// 256 thr = 4 waves; block tile 128 rows x 1024 cols; grid = 64*8 = 512.
// 32 column-steps of 32 cols. Wave owns 32 rows (afrag[2][8] = 64 VGPR).
// Buffer k (16 KB) holds cols [colbase+k'*32, +32) where k' = step, k = step%3:
//   byte = kc*2048 + g*512 + col*16  holds zn[col0+col][kc*32 + g*8 .. +8]
// Step s: {issue 4 gload_lds -> buf[(s+2)%3]} {2 phases: 8 ds_read + 16 MFMA +
// 8 exp2 each, setprio around MFMA} {s_waitcnt vmcnt(4); s_barrier} (manual).
__global__ __launch_bounds__(256, 2) void k_simsum(const unsigned short* __restrict__ zn,
                                                   float* __restrict__ partial) {
    __shared__ unsigned short buf0[32 * DIM];   // 16 KB each, SEPARATE objects
    __shared__ unsigned short buf1[32 * DIM];
    __shared__ unsigned short buf2[32 * DIM];

    int bid = blockIdx.x;
    int rb = bid & 63;        // 64 row-blocks of 128
    int cc = bid >> 6;        // 8 col-chunks of 1024
    int rowbase = rb * 128;
    int colbase = cc * 1024;
    int tid = threadIdx.x, lane = tid & 63, w = tid >> 6;   // w in 0..3
    int cl = lane & 15, g = lane >> 4;

    // A fragments: lane holds zn[rowbase + w*32 + rt*16 + cl][kc*32 + g*8 .. +8]
    s16x8 afrag[2][8];
    #pragma unroll
    for (int rt = 0; rt < 2; ++rt) {
        int row = rowbase + w * 32 + rt * 16 + cl;
        const unsigned short* ap = zn + (size_t)row * DIM + g * 8;
        #pragma unroll
        for (int kc = 0; kc < 8; ++kc)
            afrag[rt][kc] = *(const s16x8*)(ap + kc * 32);
    }

    float pp[2][4];
    #pragma unroll
    for (int rt = 0; rt < 2; ++rt)
        #pragma unroll
        for (int r = 0; r < 4; ++r) pp[rt][r] = 0.0f;

    // stage step-s column strip (32 cols x 256 K = 16 KB) into the named buffer.
    // wave w covers kc = {2w, 2w+1}; lane: col = lane&31, g-half = lane>>5.
    auto stage_into = [&](char* bufbase, int s) {
        const unsigned short* p = zn + (size_t)(colbase + s * 32 + (lane & 31)) * DIM
                                  + (lane >> 5) * 8;
        char* d = bufbase + (2 * w) * 2048;
        gload_lds16(p + (2 * w) * 32,          d);           // kc=2w,   ghalf=0
        gload_lds16(p + (2 * w) * 32 + 8,      d + 1024);    // kc=2w,   ghalf=1
        gload_lds16(p + (2 * w + 1) * 32,      d + 2048);    // kc=2w+1, ghalf=0
        gload_lds16(p + (2 * w + 1) * 32 + 8,  d + 3072);    // kc=2w+1, ghalf=1
    };

    #define STEP(BUFR, BUFW, SIDX, DO_STAGE, WAITSTR)                              \
        {                                                                          \
            if (DO_STAGE) stage_into((char*)BUFW, (SIDX) + 2);                     \
            const char* lbase_ = (const char*)BUFR;                               \
            _Pragma("unroll")                                                      \
            for (int ct = 0; ct < 2; ++ct) {                                       \
                f32x4 acc0 = (f32x4){0.f,0.f,0.f,0.f};                             \
                f32x4 acc1 = (f32x4){0.f,0.f,0.f,0.f};                             \
                __builtin_amdgcn_s_setprio(1);                                     \
                _Pragma("unroll")                                                  \
                for (int kc = 0; kc < 8; ++kc) {                                   \
                    s16x8 bfrag = *(const s16x8*)(lbase_ + kc * 2048 + g * 512 +   \
                                                  (ct * 16 + cl) * 16);            \
                    acc0 = __builtin_amdgcn_mfma_f32_16x16x32_bf16(                \
                               afrag[0][kc], bfrag, acc0, 0, 0, 0);                \
                    acc1 = __builtin_amdgcn_mfma_f32_16x16x32_bf16(                \
                               afrag[1][kc], bfrag, acc1, 0, 0, 0);                \
                }                                                                  \
                __builtin_amdgcn_s_setprio(0);                                     \
                _Pragma("unroll")                                                  \
                for (int r = 0; r < 4; ++r) {                                      \
                    pp[0][r] += __builtin_amdgcn_exp2f(acc0[r]);                   \
                    pp[1][r] += __builtin_amdgcn_exp2f(acc1[r]);                   \
                }                                                                  \
            }                                                                      \
            asm volatile(WAITSTR ::: "memory");                                    \
        }

    // prologue: buffers for steps 0 and 1 in flight; wait step-0's 4 done.
    stage_into((char*)buf0, 0);
    stage_into((char*)buf1, 1);
    asm volatile("s_waitcnt vmcnt(4)\ns_barrier" ::: "memory");

    #pragma unroll 1
    for (int s3 = 0; s3 < 30; s3 += 3) {
        STEP(buf0, buf2, s3,     true, "s_waitcnt vmcnt(4)\ns_barrier")
        STEP(buf1, buf0, s3 + 1, true, "s_waitcnt vmcnt(4)\ns_barrier")
        STEP(buf2, buf1, s3 + 2, true, "s_waitcnt vmcnt(4)\ns_barrier")
    }
    STEP(buf0, buf2, 30, false, "s_waitcnt vmcnt(0)\ns_barrier")
    STEP(buf1, buf0, 31, false, "")
    #undef STEP

    // row-partials: reduce across the 16 col-lanes (cl) within each g-group
    #pragma unroll
    for (int rt = 0; rt < 2; ++rt) {
        #pragma unroll
        for (int r = 0; r < 4; ++r) {
            float v = pp[rt][r];
            v += __shfl_xor(v, 1);
            v += __shfl_xor(v, 2);
            v += __shfl_xor(v, 4);
            v += __shfl_xor(v, 8);
            if (cl == 0)
                partial[(size_t)cc * N2 + rowbase + w * 32 + rt * 16 + g * 4 + r] = v;
        }
    }
}

// ---- K3: per-row loss over 32 blocks; last block finishes the mean ----
__global__ __launch_bounds__(256) void k_loss(const float* __restrict__ partial,
                                              const float* __restrict__ diag,
                                              const float* __restrict__ posv,
                                              float* __restrict__ blocksum,
                                              unsigned int* __restrict__ counter,
                                              float* __restrict__ out) {
    int row = blockIdx.x * 256 + threadIdx.x;
    float sum = 0.0f;
    #pragma unroll
    for (int c = 0; c < 8; ++c) sum += partial[(size_t)c * N2 + row];
    sum -= __builtin_amdgcn_exp2f(diag[row]);           // remove diagonal term
    float lr = __builtin_amdgcn_logf(sum) * LN2 - posv[row & (BROWS - 1)];
    lr = wave_reduce(lr);
    __shared__ float red[4];
    if ((threadIdx.x & 63) == 0) red[threadIdx.x >> 6] = lr;
    __syncthreads();
    if (threadIdx.x == 0) {
        blocksum[blockIdx.x] = red[0] + red[1] + red[2] + red[3];
        __threadfence();                                  // publish blocksum
        unsigned int old = atomicAdd(counter, 1u);        // device-scope
        if (old == 31u) {                                 // last block finishes
            __threadfence();                              // acquire
            volatile const float* bs = blocksum;
            float t = 0.0f;
            for (int i = 0; i < 32; ++i) t += bs[i];
            out[0] = t * (1.0f / N2);
        }
    }
}

extern "C" void kernel_launch(void* const* d_in, const int* in_sizes, int n_in,
                              void* d_out, int out_size, void* d_ws, size_t ws_size,
                              hipStream_t stream) {
    const float* zi = (const float*)d_in[0];
    const float* zj = (const float*)d_in[1];
    float* out = (float*)d_out;

    char* ws = (char*)d_ws;
    unsigned short* zn    = (unsigned short*)ws;                       // 4 MB
    float* diag           = (float*)(ws + (4u << 20));                 // 32 KB
    float* posv           = (float*)(ws + (4u << 20) + (32u << 10));   // 16 KB
    float* blocksum       = (float*)(ws + (4u << 20) + (48u << 10));   // 128 B
    unsigned int* counter = (unsigned int*)(ws + (4u << 20) + (52u << 10));
    float* partial        = (float*)(ws + (4u << 20) + (64u << 10));   // 256 KB (8 slots)

    k_norm_pos<<<BROWS / 4, 256, 0, stream>>>(zi, zj, zn, diag, posv, counter);
    k_simsum<<<512, 256, 0, stream>>>(zn, partial);
    k_loss<<<32, 256, 0, stream>>>(partial, diag, posv, blocksum, counter, out);
}